// Round 1
// baseline (263.512 us; speedup 1.0000x reference)
//
#include <hip/hip_runtime.h>

#define B_ 8
#define C_ 64
#define H_ 376
#define W_ 1241
#define NPTS_ 30000
#define DIN_ 80
#define NCLS_ 19
#define NTOT (B_*NPTS_)          // 240000
#define HW_ ((size_t)H_*W_)      // 466616
#define CHW_ ((size_t)C_*HW_)
#define WSUB 376
#define WHALF 188

__device__ __forceinline__ void fma4(float4& a, float s, const float4 b) {
    a.x = fmaf(s, b.x, a.x); a.y = fmaf(s, b.y, a.y);
    a.z = fmaf(s, b.z, a.z); a.w = fmaf(s, b.w, a.w);
}

// ---------------- Kernel P: fold A = W2 @ Wc1 ([128][20] padded), c1 = b2@Wc1 + bc1 ([20] padded)
__global__ void precompute_kernel(const float* __restrict__ W2, const float* __restrict__ b2,
                                  const float* __restrict__ Wc1, const float* __restrict__ bc1,
                                  float* __restrict__ wsA, float* __restrict__ wsc1) {
    int t = blockIdx.x * 256 + threadIdx.x;
    if (t < 128 * 20) {
        int k = t / 20, j = t % 20;
        float v = 0.f;
        if (j < 19) {
            for (int c = 0; c < 64; ++c) v += W2[k * 64 + c] * Wc1[c * 19 + j];
        }
        wsA[t] = v;
    } else if (t < 128 * 20 + 20) {
        int j = t - 128 * 20;
        float v = 0.f;
        if (j < 19) {
            v = bc1[j];
            for (int c = 0; c < 64; ++c) v += b2[c] * Wc1[c * 19 + j];
        }
        wsc1[j] = v;
    }
}

// ---------------- Transpose kernel: feats[b][c][h][0..375] -> fsub[(b*376+h)*376 + w][c]
__global__ __launch_bounds__(256) void transpose_kernel(const float* __restrict__ feats,
                                                        float* __restrict__ fsub) {
    int blk = blockIdx.x;
    int half = blk & 1;
    int bh = blk >> 1;             // b*376 + h
    int b = bh / H_;
    int h = bh % H_;
    int w0 = half * WHALF;
    __shared__ float tile[64 * 189];
    const float* src = feats + (size_t)b * CHW_ + (size_t)h * W_ + w0;
    for (int j = threadIdx.x; j < 64 * WHALF; j += 256) {
        int c = j / WHALF, w = j % WHALF;
        tile[c * 189 + w] = src[(size_t)c * HW_ + w];
    }
    __syncthreads();
    float4* dst4 = (float4*)(fsub + ((size_t)bh * WSUB + w0) * 64);
    for (int j = threadIdx.x; j < WHALF * 16; j += 256) {
        int w = j >> 4, c4 = j & 15;
        float4 v;
        v.x = tile[(c4 * 4 + 0) * 189 + w];
        v.y = tile[(c4 * 4 + 1) * 189 + w];
        v.z = tile[(c4 * 4 + 2) * 189 + w];
        v.w = tile[(c4 * 4 + 3) * 189 + w];
        dst4[(size_t)w * 16 + c4] = v;
    }
}

// ---------------- Fused per-point kernel
__device__ __forceinline__ void acc_rows(float4* s14, float4* s24, float g,
                                         const float* sA, const float* sWc2, int k) {
    const float4* ar = (const float4*)(sA + k * 20);
    const float4* cr = (const float4*)(sWc2 + k * 20);
    #pragma unroll
    for (int j4 = 0; j4 < 5; ++j4) { fma4(s14[j4], g, ar[j4]); fma4(s24[j4], g, cr[j4]); }
}

__device__ __forceinline__ void acc_row1(float4* s14, float g, const float* sA, int k) {
    const float4* ar = (const float4*)(sA + k * 20);
    #pragma unroll
    for (int j4 = 0; j4 < 5; ++j4) fma4(s14[j4], g, ar[j4]);
}

template <int DIRECT>
__global__ __launch_bounds__(256) void fused_kernel(
    const float* __restrict__ feats, const float* __restrict__ fsub,
    const float* __restrict__ fusion, const int* __restrict__ idx,
    const float* __restrict__ W1, const float* __restrict__ b1,
    const float* __restrict__ Wc2, const float* __restrict__ bc2,
    const float* __restrict__ wsA, const float* __restrict__ wsc1,
    float* __restrict__ out) {
    __shared__ __align__(16) float sW1[80 * 64];
    __shared__ __align__(16) float sA[128 * 20];
    __shared__ __align__(16) float sWc2[64 * 20];
    __shared__ __align__(16) float sb1[64];
    __shared__ __align__(16) float sc1[20];
    __shared__ __align__(16) float sbc2[20];
    int tid = threadIdx.x;
    for (int t = tid; t < 80 * 64; t += 256) sW1[t] = W1[t];
    for (int t = tid; t < 128 * 20; t += 256) sA[t] = wsA[t];
    for (int t = tid; t < 64 * 20; t += 256) {
        int k = t / 20, j = t % 20;
        sWc2[t] = (j < 19) ? Wc2[k * 19 + j] : 0.f;
    }
    if (tid < 64) sb1[tid] = b1[tid];
    if (tid < 20) sc1[tid] = wsc1[tid];
    if (tid < 20) sbc2[tid] = (tid < 19) ? bc2[tid] : 0.f;
    __syncthreads();

    int i0 = blockIdx.x * 256 + tid;
    bool act = (i0 < NTOT);
    int i = act ? i0 : 0;
    int b = i / NPTS_;
    int2 hw = ((const int2*)idx)[i];
    int h = hw.x, w = hw.y;

    // f1 = relu(fusion_row @ W1 + b1)
    float4 f14[16];
    #pragma unroll
    for (int c4 = 0; c4 < 16; ++c4) f14[c4] = ((const float4*)sb1)[c4];
    const float4* fu4 = (const float4*)(fusion + (size_t)i * DIN_);
    for (int d4 = 0; d4 < DIN_ / 4; ++d4) {
        float4 x = fu4[d4];
        const float* wr = sW1 + d4 * 256;
        #pragma unroll
        for (int c4 = 0; c4 < 16; ++c4) {
            fma4(f14[c4], x.x, *(const float4*)(wr + c4 * 4));
            fma4(f14[c4], x.y, *(const float4*)(wr + 64 + c4 * 4));
            fma4(f14[c4], x.z, *(const float4*)(wr + 128 + c4 * 4));
            fma4(f14[c4], x.w, *(const float4*)(wr + 192 + c4 * 4));
        }
    }
    #pragma unroll
    for (int c4 = 0; c4 < 16; ++c4) {
        f14[c4].x = fmaxf(f14[c4].x, 0.f);
        f14[c4].y = fmaxf(f14[c4].y, 0.f);
        f14[c4].z = fmaxf(f14[c4].z, 0.f);
        f14[c4].w = fmaxf(f14[c4].w, 0.f);
    }

    float4 s14[5], s24[5];
    #pragma unroll
    for (int j4 = 0; j4 < 5; ++j4) {
        s14[j4] = ((const float4*)sc1)[j4];
        s24[j4] = ((const float4*)sbc2)[j4];
    }

    // gathered-feature contribution (rows 0..63 of A, plus Wc2 head)
    if (DIRECT) {
        const float* fb = feats + (size_t)b * CHW_ + (size_t)h * W_ + w;
        for (int k = 0; k < 64; ++k) {
            float g = fb[(size_t)k * HW_];
            acc_rows(s14, s24, g, sA, sWc2, k);
        }
    } else {
        const float4* gp = (const float4*)(fsub + (((size_t)b * H_ + h) * WSUB + w) * 64);
        #pragma unroll 4
        for (int k4 = 0; k4 < 16; ++k4) {
            float4 g4 = gp[k4];
            acc_rows(s14, s24, g4.x, sA, sWc2, k4 * 4 + 0);
            acc_rows(s14, s24, g4.y, sA, sWc2, k4 * 4 + 1);
            acc_rows(s14, s24, g4.z, sA, sWc2, k4 * 4 + 2);
            acc_rows(s14, s24, g4.w, sA, sWc2, k4 * 4 + 3);
        }
    }

    // f1 contribution (rows 64..127 of A)
    #pragma unroll 4
    for (int k4 = 0; k4 < 16; ++k4) {
        float4 f = f14[k4];
        acc_row1(s14, f.x, sA, 64 + k4 * 4 + 0);
        acc_row1(s14, f.y, sA, 64 + k4 * 4 + 1);
        acc_row1(s14, f.z, sA, 64 + k4 * 4 + 2);
        acc_row1(s14, f.w, sA, 64 + k4 * 4 + 3);
    }

    if (act) {
        float* o1 = out + (size_t)i * 19;
        float* o2 = out + (size_t)NTOT * 19 + (size_t)i * 19;
        const float* s1s = (const float*)s14;
        const float* s2s = (const float*)s24;
        #pragma unroll
        for (int j = 0; j < 19; ++j) o1[j] = s1s[j];
        #pragma unroll
        for (int j = 0; j < 19; ++j) o2[j] = s2s[j];
    }
}

extern "C" void kernel_launch(void* const* d_in, const int* in_sizes, int n_in,
                              void* d_out, int out_size, void* d_ws, size_t ws_size,
                              hipStream_t stream) {
    const float* feats  = (const float*)d_in[0];
    const float* fusion = (const float*)d_in[1];
    const int*   idx    = (const int*)d_in[2];
    const float* W1  = (const float*)d_in[3];
    const float* b1  = (const float*)d_in[4];
    const float* W2  = (const float*)d_in[5];
    const float* b2  = (const float*)d_in[6];
    const float* Wc1 = (const float*)d_in[7];
    const float* bc1 = (const float*)d_in[8];
    const float* Wc2 = (const float*)d_in[9];
    const float* bc2 = (const float*)d_in[10];
    float* out = (float*)d_out;

    float* wsA  = (float*)d_ws;              // 128*20 floats
    float* wsc1 = wsA + 128 * 20;            // 20 floats
    float* fsub = (float*)((char*)d_ws + 16384);
    size_t need = 16384 + (size_t)B_ * H_ * WSUB * 64 * sizeof(float);

    precompute_kernel<<<11, 256, 0, stream>>>(W2, b2, Wc1, bc1, wsA, wsc1);

    int blocks = (NTOT + 255) / 256;
    if (ws_size >= need) {
        transpose_kernel<<<B_ * H_ * 2, 256, 0, stream>>>(feats, fsub);
        fused_kernel<0><<<blocks, 256, 0, stream>>>(feats, fsub, fusion, idx, W1, b1,
                                                    Wc2, bc2, wsA, wsc1, out);
    } else {
        fused_kernel<1><<<blocks, 256, 0, stream>>>(feats, fsub, fusion, idx, W1, b1,
                                                    Wc2, bc2, wsA, wsc1, out);
    }
}

// Round 2
// 179.827 us; speedup vs baseline: 1.4654x; 1.4654x over previous
//
#include <hip/hip_runtime.h>

typedef unsigned int u32;
typedef unsigned short u16;
typedef unsigned long long u64;
typedef __attribute__((ext_vector_type(8))) short short8;
typedef __attribute__((ext_vector_type(4))) float f32x4;

#define NB 8
#define NC 64
#define NH 376
#define NWID 1241
#define NPTS 30000
#define NDIN 80
#define NTOTP 240000
#define PPB 141376              // 376*376 positions per sample
#define NPOS 1131008            // 8*PPB  (multiple of 64)
#define HW_ ((size_t)NH*NWID)
#define CHW_ ((size_t)NC*HW_)

// workspace layout (new path)
#define OFF_WPROJ 0             // u16[48*64]
#define OFF_W1T   8192          // u16[64*96]
#define OFF_WBOT  24576         // u16[32*64]
#define OFF_CBIAS 28672         // float[48]
#define OFF_PROJ  32768         // u16[NPOS*40]
#define WS_NEED   ((size_t)32768 + (size_t)NPOS*40*2)

__device__ __forceinline__ u16 f2bf(float f) {
    u32 u = __builtin_bit_cast(u32, f);
    return (u16)((u + 0x7FFFu + ((u >> 16) & 1u)) >> 16);
}
__device__ __forceinline__ float bf2f(u32 lo16) {
    return __builtin_bit_cast(float, lo16 << 16);
}
__device__ __forceinline__ u32 packbf2(float a, float b) {
    return (u32)f2bf(a) | ((u32)f2bf(b) << 16);
}
#define MFMA16(a,b,c) __builtin_amdgcn_mfma_f32_16x16x32_bf16(a, b, c, 0, 0, 0)

// ================= prep: build bf16 weight tables + folded biases ===========
// Wproj[j][ch] (j<48): j<20 -> A[ch][j] = sum_c W2[ch][c]*Wc1[c][j] (j==19 pad 0)
//                      20<=j<39 -> Wc2[ch][j-20], else 0
// W1t[c][d96] = W1[d][c] (d<80 else 0)
// Wbot[j][c] (j<32): j<19 -> A[64+c][j], else 0
// cbias[j]: j<19 -> bc1[j]+b2@Wc1[:,j]; 20<=j<39 -> bc2[j-20]; else 0
__global__ void prep_kernel(const float* __restrict__ W1, const float* __restrict__ W2,
                            const float* __restrict__ b2, const float* __restrict__ Wc1,
                            const float* __restrict__ bc1, const float* __restrict__ Wc2,
                            const float* __restrict__ bc2,
                            u16* __restrict__ Wproj, u16* __restrict__ W1t,
                            u16* __restrict__ Wbot, float* __restrict__ cbias) {
    int t = blockIdx.x * 256 + threadIdx.x;
    if (t < 3072) {
        int j = t >> 6, ch = t & 63;
        float v = 0.f;
        if (j < 19) { for (int c = 0; c < 64; ++c) v += W2[ch * 64 + c] * Wc1[c * 19 + j]; }
        else if (j >= 20 && j < 39) v = Wc2[ch * 19 + (j - 20)];
        Wproj[t] = f2bf(v);
    } else if (t < 3072 + 6144) {
        int q = t - 3072; int c = q / 96, d = q % 96;
        W1t[q] = f2bf(d < 80 ? W1[d * 64 + c] : 0.f);
    } else if (t < 3072 + 6144 + 2048) {
        int q = t - 9216; int j = q >> 6, c = q & 63;
        float v = 0.f;
        if (j < 19) { for (int cc = 0; cc < 64; ++cc) v += W2[(64 + c) * 64 + cc] * Wc1[cc * 19 + j]; }
        Wbot[q] = f2bf(v);
    } else if (t < 3072 + 6144 + 2048 + 48) {
        int j = t - 11264;
        float v = 0.f;
        if (j < 19) { v = bc1[j]; for (int c = 0; c < 64; ++c) v += b2[c] * Wc1[c * 19 + j]; }
        else if (j >= 20 && j < 39) v = bc2[j - 20];
        cbias[j] = v;
    }
}

// ================= projection: proj[pos][j<40] = g(pos).[Atop|Wc2] + bias ====
// One wave = 64 positions. C^T form: A-op = Wproj rows j, B-op = feats (already [ch][pos]).
__global__ __launch_bounds__(256) void proj_kernel(const float* __restrict__ feats,
        const u16* __restrict__ Wproj, const float* __restrict__ cbias,
        u16* __restrict__ proj) {
    int tid = threadIdx.x;
    int lane = tid & 63, wid = tid >> 6;
    int l15 = lane & 15, l4 = lane >> 4;
    int p0 = (blockIdx.x * 4 + wid) * 64;

    short8 wf[3][2];
    #pragma unroll
    for (int mt = 0; mt < 3; ++mt)
        #pragma unroll
        for (int kt = 0; kt < 2; ++kt)
            wf[mt][kt] = *(const short8*)(Wproj + (mt * 16 + l15) * 64 + kt * 32 + l4 * 8);
    float bias[3][4];
    #pragma unroll
    for (int mt = 0; mt < 3; ++mt)
        #pragma unroll
        for (int q = 0; q < 4; ++q)
            bias[mt][q] = cbias[mt * 16 + l4 * 4 + q];

    #pragma unroll
    for (int nt = 0; nt < 4; ++nt) {
        u32 p = (u32)(p0 + nt * 16 + l15);
        u32 b = p / PPB, r = p % PPB;
        u32 h = r / 376u, w = r % 376u;
        const float* base = feats + (size_t)b * CHW_ + (size_t)h * NWID + w;
        short8 bfrag[2];
        #pragma unroll
        for (int kt = 0; kt < 2; ++kt) {
            int ch0 = kt * 32 + l4 * 8;
            float g[8];
            #pragma unroll
            for (int e = 0; e < 8; ++e) g[e] = base[(size_t)(ch0 + e) * HW_];
            short8 s;
            #pragma unroll
            for (int e = 0; e < 8; ++e) s[e] = (short)f2bf(g[e]);
            bfrag[kt] = s;
        }
        f32x4 acc[3];
        #pragma unroll
        for (int mt = 0; mt < 3; ++mt) {
            f32x4 a = {bias[mt][0], bias[mt][1], bias[mt][2], bias[mt][3]};
            acc[mt] = a;
        }
        #pragma unroll
        for (int kt = 0; kt < 2; ++kt)
            #pragma unroll
            for (int mt = 0; mt < 3; ++mt)
                acc[mt] = MFMA16(wf[mt][kt], bfrag[kt], acc[mt]);
        // store: this lane's column position is p; rows j0 = mt*16+l4*4
        #pragma unroll
        for (int mt = 0; mt < 3; ++mt) {
            if (mt == 2 && l4 >= 2) continue;   // j >= 40 pad
            uint2 st;
            st.x = packbf2(acc[mt][0], acc[mt][1]);
            st.y = packbf2(acc[mt][2], acc[mt][3]);
            *(uint2*)(proj + (size_t)p * 40 + mt * 16 + l4 * 4) = st;
        }
    }
}

// ================= fused: f1 = relu(X@W1+b1); S^T = Wbot^T.f1^T + gather(proj) =
__global__ __launch_bounds__(256) void fused2_kernel(const float* __restrict__ fusion,
        const int* __restrict__ idx, const float* __restrict__ b1,
        const u16* __restrict__ W1t, const u16* __restrict__ Wbot,
        const u16* __restrict__ proj, float* __restrict__ out) {
    __shared__ __align__(16) u32 slds[4][16][32];   // per-wave 2KB slice, XOR-swizzled
    int tid = threadIdx.x;
    int lane = tid & 63, wid = tid >> 6;
    int l15 = lane & 15, l4 = lane >> 4;
    int t = blockIdx.x * 4 + wid;
    if (t >= NTOTP / 64) return;                    // no barriers in kernel -> safe
    int i0 = t * 64;

    short8 w1f[4][3];
    #pragma unroll
    for (int mt = 0; mt < 4; ++mt)
        #pragma unroll
        for (int kt = 0; kt < 3; ++kt)
            w1f[mt][kt] = *(const short8*)(W1t + (mt * 16 + l15) * 96 + kt * 32 + l4 * 8);
    short8 wbf[2][2];
    #pragma unroll
    for (int mt = 0; mt < 2; ++mt)
        #pragma unroll
        for (int kt = 0; kt < 2; ++kt)
            wbf[mt][kt] = *(const short8*)(Wbot + (mt * 16 + l15) * 64 + kt * 32 + l4 * 8);
    float b1r[4][4];
    #pragma unroll
    for (int mt = 0; mt < 4; ++mt)
        #pragma unroll
        for (int q = 0; q < 4; ++q)
            b1r[mt][q] = b1[mt * 16 + l4 * 4 + q];

    u32* myl = &slds[wid][0][0];
    #pragma unroll 1
    for (int nt = 0; nt < 4; ++nt) {
        int ip = i0 + nt * 16 + l15;               // this lane's column point
        int2 hw = ((const int2*)idx)[ip];
        size_t pos = ((size_t)(u32)(ip / NPTS) * 376 + (u32)hw.x) * 376 + (u32)hw.y;
        const u16* prow = proj + pos * 40;
        f32x4 acc[3];
        #pragma unroll
        for (int mt = 0; mt < 3; ++mt) {
            if (mt == 2 && l4 >= 2) { f32x4 z = {0.f, 0.f, 0.f, 0.f}; acc[mt] = z; }
            else {
                uint2 v = *(const uint2*)(prow + mt * 16 + l4 * 4);
                f32x4 a = {bf2f(v.x & 0xffffu), bf2f(v.x >> 16),
                           bf2f(v.y & 0xffffu), bf2f(v.y >> 16)};
                acc[mt] = a;
            }
        }
        // GEMM1: C1^T[c][pos] = W1t . X^T
        const float* frow = fusion + (size_t)ip * NDIN;
        f32x4 c1[4];
        #pragma unroll
        for (int mt = 0; mt < 4; ++mt) {
            f32x4 a = {b1r[mt][0], b1r[mt][1], b1r[mt][2], b1r[mt][3]};
            c1[mt] = a;
        }
        #pragma unroll
        for (int kt = 0; kt < 3; ++kt) {
            short8 xf = {0, 0, 0, 0, 0, 0, 0, 0};
            int d0 = kt * 32 + l4 * 8;
            if (d0 < 80) {
                float4 a = *(const float4*)(frow + d0);
                float4 bq = *(const float4*)(frow + d0 + 4);
                short8 s;
                s[0] = (short)f2bf(a.x);  s[1] = (short)f2bf(a.y);
                s[2] = (short)f2bf(a.z);  s[3] = (short)f2bf(a.w);
                s[4] = (short)f2bf(bq.x); s[5] = (short)f2bf(bq.y);
                s[6] = (short)f2bf(bq.z); s[7] = (short)f2bf(bq.w);
                xf = s;
            }
            #pragma unroll
            for (int mt = 0; mt < 4; ++mt) c1[mt] = MFMA16(w1f[mt][kt], xf, c1[mt]);
        }
        // relu -> bf16 -> swizzled LDS [pos][c]
        #pragma unroll
        for (int mt = 0; mt < 4; ++mt) {
            float x0 = fmaxf(c1[mt][0], 0.f), x1 = fmaxf(c1[mt][1], 0.f);
            float x2 = fmaxf(c1[mt][2], 0.f), x3 = fmaxf(c1[mt][3], 0.f);
            u32 lo = packbf2(x0, x1), hi = packbf2(x2, x3);
            int c0 = mt * 16 + l4 * 4;
            int gsw = (c0 >> 3) ^ (l15 & 7);
            *(u64*)(myl + l15 * 32 + gsw * 4 + ((c0 & 4) >> 1)) = (u64)lo | ((u64)hi << 32);
        }
        // GEMM2: S^T += Wbot . f1^T   (rows j<32; j>=20 rows are zero weights)
        #pragma unroll
        for (int kt = 0; kt < 2; ++kt) {
            int gsw = (kt * 4 + l4) ^ (l15 & 7);
            short8 f1f = *(const short8*)(myl + l15 * 32 + gsw * 4);
            #pragma unroll
            for (int mt = 0; mt < 2; ++mt) acc[mt] = MFMA16(wbf[mt][kt], f1f, acc[mt]);
        }
        // stores: head1 j<19, head2 j-20<19
        #pragma unroll
        for (int mt = 0; mt < 3; ++mt) {
            #pragma unroll
            for (int q = 0; q < 4; ++q) {
                int j = mt * 16 + l4 * 4 + q;
                float v = acc[mt][q];
                if (j < 19) out[(size_t)ip * 19 + j] = v;
                else if (j >= 20 && j < 39) out[(size_t)NTOTP * 19 + (size_t)ip * 19 + (j - 20)] = v;
            }
        }
    }
}

// ================= fallback (tiny ws): round-1 direct path ==================
__global__ void precompute_old(const float* __restrict__ W2, const float* __restrict__ b2,
                               const float* __restrict__ Wc1, const float* __restrict__ bc1,
                               float* __restrict__ wsA, float* __restrict__ wsc1) {
    int t = blockIdx.x * 256 + threadIdx.x;
    if (t < 128 * 20) {
        int k = t / 20, j = t % 20;
        float v = 0.f;
        if (j < 19) for (int c = 0; c < 64; ++c) v += W2[k * 64 + c] * Wc1[c * 19 + j];
        wsA[t] = v;
    } else if (t < 128 * 20 + 20) {
        int j = t - 128 * 20;
        float v = 0.f;
        if (j < 19) { v = bc1[j]; for (int c = 0; c < 64; ++c) v += b2[c] * Wc1[c * 19 + j]; }
        wsc1[j] = v;
    }
}

__device__ __forceinline__ void fma4o(float4& a, float s, const float4 b) {
    a.x = fmaf(s, b.x, a.x); a.y = fmaf(s, b.y, a.y);
    a.z = fmaf(s, b.z, a.z); a.w = fmaf(s, b.w, a.w);
}

__global__ __launch_bounds__(256) void fused_old(
    const float* __restrict__ feats, const float* __restrict__ fusion,
    const int* __restrict__ idx, const float* __restrict__ W1, const float* __restrict__ b1,
    const float* __restrict__ Wc2, const float* __restrict__ bc2,
    const float* __restrict__ wsA, const float* __restrict__ wsc1, float* __restrict__ out) {
    __shared__ __align__(16) float sW1[80 * 64];
    __shared__ __align__(16) float sA[128 * 20];
    __shared__ __align__(16) float sWc2[64 * 20];
    __shared__ __align__(16) float sb1[64];
    __shared__ __align__(16) float sc1[20];
    __shared__ __align__(16) float sbc2[20];
    int tid = threadIdx.x;
    for (int t = tid; t < 80 * 64; t += 256) sW1[t] = W1[t];
    for (int t = tid; t < 128 * 20; t += 256) sA[t] = wsA[t];
    for (int t = tid; t < 64 * 20; t += 256) {
        int k = t / 20, j = t % 20;
        sWc2[t] = (j < 19) ? Wc2[k * 19 + j] : 0.f;
    }
    if (tid < 64) sb1[tid] = b1[tid];
    if (tid < 20) sc1[tid] = wsc1[tid];
    if (tid < 20) sbc2[tid] = (tid < 19) ? bc2[tid] : 0.f;
    __syncthreads();
    int i0 = blockIdx.x * 256 + tid;
    bool act = (i0 < NTOTP);
    int i = act ? i0 : 0;
    int b = i / NPTS;
    int2 hw = ((const int2*)idx)[i];
    float4 f14[16];
    #pragma unroll
    for (int c4 = 0; c4 < 16; ++c4) f14[c4] = ((const float4*)sb1)[c4];
    const float4* fu4 = (const float4*)(fusion + (size_t)i * NDIN);
    for (int d4 = 0; d4 < NDIN / 4; ++d4) {
        float4 x = fu4[d4];
        const float* wr = sW1 + d4 * 256;
        #pragma unroll
        for (int c4 = 0; c4 < 16; ++c4) {
            fma4o(f14[c4], x.x, *(const float4*)(wr + c4 * 4));
            fma4o(f14[c4], x.y, *(const float4*)(wr + 64 + c4 * 4));
            fma4o(f14[c4], x.z, *(const float4*)(wr + 128 + c4 * 4));
            fma4o(f14[c4], x.w, *(const float4*)(wr + 192 + c4 * 4));
        }
    }
    #pragma unroll
    for (int c4 = 0; c4 < 16; ++c4) {
        f14[c4].x = fmaxf(f14[c4].x, 0.f); f14[c4].y = fmaxf(f14[c4].y, 0.f);
        f14[c4].z = fmaxf(f14[c4].z, 0.f); f14[c4].w = fmaxf(f14[c4].w, 0.f);
    }
    float4 s14[5], s24[5];
    #pragma unroll
    for (int j4 = 0; j4 < 5; ++j4) { s14[j4] = ((const float4*)sc1)[j4]; s24[j4] = ((const float4*)sbc2)[j4]; }
    const float* fb = feats + (size_t)b * CHW_ + (size_t)hw.x * NWID + hw.y;
    for (int k = 0; k < 64; ++k) {
        float g = fb[(size_t)k * HW_];
        const float4* ar = (const float4*)(sA + k * 20);
        const float4* cr = (const float4*)(sWc2 + k * 20);
        #pragma unroll
        for (int j4 = 0; j4 < 5; ++j4) { fma4o(s14[j4], g, ar[j4]); fma4o(s24[j4], g, cr[j4]); }
    }
    const float* f1s = (const float*)f14;
    for (int k = 0; k < 64; ++k) {
        float g = f1s[k];
        const float4* ar = (const float4*)(sA + (64 + k) * 20);
        #pragma unroll
        for (int j4 = 0; j4 < 5; ++j4) fma4o(s14[j4], g, ar[j4]);
    }
    if (act) {
        float* o1 = out + (size_t)i * 19;
        float* o2 = out + (size_t)NTOTP * 19 + (size_t)i * 19;
        const float* s1s = (const float*)s14;
        const float* s2s = (const float*)s24;
        #pragma unroll
        for (int j = 0; j < 19; ++j) o1[j] = s1s[j];
        #pragma unroll
        for (int j = 0; j < 19; ++j) o2[j] = s2s[j];
    }
}

// ================= launch ====================================================
extern "C" void kernel_launch(void* const* d_in, const int* in_sizes, int n_in,
                              void* d_out, int out_size, void* d_ws, size_t ws_size,
                              hipStream_t stream) {
    const float* feats  = (const float*)d_in[0];
    const float* fusion = (const float*)d_in[1];
    const int*   idx    = (const int*)d_in[2];
    const float* W1  = (const float*)d_in[3];
    const float* b1  = (const float*)d_in[4];
    const float* W2  = (const float*)d_in[5];
    const float* b2  = (const float*)d_in[6];
    const float* Wc1 = (const float*)d_in[7];
    const float* bc1 = (const float*)d_in[8];
    const float* Wc2 = (const float*)d_in[9];
    const float* bc2 = (const float*)d_in[10];
    float* out = (float*)d_out;
    char* ws = (char*)d_ws;

    if (ws_size >= WS_NEED) {
        u16*   Wproj = (u16*)(ws + OFF_WPROJ);
        u16*   W1t   = (u16*)(ws + OFF_W1T);
        u16*   Wbot  = (u16*)(ws + OFF_WBOT);
        float* cbias = (float*)(ws + OFF_CBIAS);
        u16*   proj  = (u16*)(ws + OFF_PROJ);
        prep_kernel<<<45, 256, 0, stream>>>(W1, W2, b2, Wc1, bc1, Wc2, bc2,
                                            Wproj, W1t, Wbot, cbias);
        proj_kernel<<<NPOS / 256, 256, 0, stream>>>(feats, Wproj, cbias, proj);
        fused2_kernel<<<(NTOTP / 64 + 3) / 4, 256, 0, stream>>>(fusion, idx, b1,
                                                                W1t, Wbot, proj, out);
    } else {
        float* wsA  = (float*)ws;
        float* wsc1 = wsA + 128 * 20;
        precompute_old<<<11, 256, 0, stream>>>(W2, b2, Wc1, bc1, wsA, wsc1);
        fused_old<<<(NTOTP + 255) / 256, 256, 0, stream>>>(feats, fusion, idx, W1, b1,
                                                           Wc2, bc2, wsA, wsc1, out);
    }
}

// Round 4
// 169.185 us; speedup vs baseline: 1.5575x; 1.0629x over previous
//
#include <hip/hip_runtime.h>

typedef unsigned int u32;
typedef unsigned short u16;
typedef unsigned long long u64;
typedef __attribute__((ext_vector_type(8))) short short8;
typedef __attribute__((ext_vector_type(4))) float f32x4;
typedef __attribute__((ext_vector_type(4))) float fv4;

#define NB 8
#define NC 64
#define NH 376
#define NWID 1241
#define NPTS 30000
#define NDIN 80
#define NTOTP 240000
#define PPB 141376              // 376*376 positions per sample
#define NPOS 1131008            // 8*PPB  (multiple of 256)
#define HW_ ((size_t)NH*NWID)
#define CHW_ ((size_t)NC*HW_)

// workspace layout (new path)
#define OFF_WPROJ 0             // u16[48*64]
#define OFF_W1T   8192          // u16[64*96]
#define OFF_WBOT  24576         // u16[32*64]
#define OFF_CBIAS 28672         // float[48]
#define OFF_PROJ  32768         // u16, 10 planes x NPOS x 4 u16 (8B per pos per plane)
#define WS_NEED   ((size_t)32768 + (size_t)NPOS*40*2)

__device__ __forceinline__ u16 f2bf(float f) {
    u32 u = __builtin_bit_cast(u32, f);
    return (u16)((u + 0x7FFFu + ((u >> 16) & 1u)) >> 16);
}
__device__ __forceinline__ float bf2f(u32 lo16) {
    return __builtin_bit_cast(float, lo16 << 16);
}
__device__ __forceinline__ u32 packbf2(float a, float b) {
    return (u32)f2bf(a) | ((u32)f2bf(b) << 16);
}
#define MFMA16(a,b,c) __builtin_amdgcn_mfma_f32_16x16x32_bf16(a, b, c, 0, 0, 0)

// ================= prep: build bf16 weight tables + folded biases ===========
__global__ void prep_kernel(const float* __restrict__ W1, const float* __restrict__ W2,
                            const float* __restrict__ b2, const float* __restrict__ Wc1,
                            const float* __restrict__ bc1, const float* __restrict__ Wc2,
                            const float* __restrict__ bc2,
                            u16* __restrict__ Wproj, u16* __restrict__ W1t,
                            u16* __restrict__ Wbot, float* __restrict__ cbias) {
    int t = blockIdx.x * 256 + threadIdx.x;
    if (t < 3072) {
        int j = t >> 6, ch = t & 63;
        float v = 0.f;
        if (j < 19) { for (int c = 0; c < 64; ++c) v += W2[ch * 64 + c] * Wc1[c * 19 + j]; }
        else if (j >= 20 && j < 39) v = Wc2[ch * 19 + (j - 20)];
        Wproj[t] = f2bf(v);
    } else if (t < 3072 + 6144) {
        int q = t - 3072; int c = q / 96, d = q % 96;
        W1t[q] = f2bf(d < 80 ? W1[d * 64 + c] : 0.f);
    } else if (t < 3072 + 6144 + 2048) {
        int q = t - 9216; int j = q >> 6, c = q & 63;
        float v = 0.f;
        if (j < 19) { for (int cc = 0; cc < 64; ++cc) v += W2[(64 + c) * 64 + cc] * Wc1[cc * 19 + j]; }
        Wbot[q] = f2bf(v);
    } else if (t < 3072 + 6144 + 2048 + 48) {
        int j = t - 11264;
        float v = 0.f;
        if (j < 19) { v = bc1[j]; for (int c = 0; c < 64; ++c) v += b2[c] * Wc1[c * 19 + j]; }
        else if (j >= 20 && j < 39) v = bc2[j - 20];
        cbias[j] = v;
    }
}

// ================= projection v3: block stages [64ch][256pos] in LDS ========
// Block = 256 consecutive positions. Wave w loads channels w*16..w*16+15 as
// dense 1KB runs (DRAM row-buffer friendly), bf16 into LDS; then each wave
// computes 64 positions via MFMA and stores to planar proj[jd][pos] (jd=j/4).
__global__ __launch_bounds__(256) void proj_kernel(const float* __restrict__ feats,
        const u16* __restrict__ Wproj, const float* __restrict__ cbias,
        u16* __restrict__ proj) {
    __shared__ __align__(16) u16 ldsA[64][264];   // row pad: 528B rows -> 2-way max on writes
    int tid = threadIdx.x;
    int lane = tid & 63, wid = tid >> 6;
    int l15 = lane & 15, l4 = lane >> 4;
    int pblk0 = blockIdx.x * 256;

    // ---- stage: 16 channels per wave, 256 positions, 4B loads in dense runs
    {
        u32 p0 = (u32)(pblk0 + lane * 4);
        u32 b = p0 / PPB;                 // float4-span never crosses b/h (PPB%4==0, 376%4==0)
        u32 r = p0 - b * PPB;
        u32 h = r / 376u, w = r - h * 376u;
        const float* base0 = feats + (size_t)b * CHW_ + (size_t)h * NWID + w;
        #pragma unroll 1
        for (int it = 0; it < 16; ++it) {
            int c = wid * 16 + it;
            const float* src = base0 + (size_t)c * HW_;
            float v0 = __builtin_nontemporal_load(src + 0);
            float v1 = __builtin_nontemporal_load(src + 1);
            float v2 = __builtin_nontemporal_load(src + 2);
            float v3 = __builtin_nontemporal_load(src + 3);
            u64 pk = (u64)packbf2(v0, v1) | ((u64)packbf2(v2, v3) << 32);
            *(u64*)&ldsA[c][lane * 4] = pk;
        }
    }
    __syncthreads();

    // ---- weight fragments + bias
    short8 wf[3][2];
    #pragma unroll
    for (int mt = 0; mt < 3; ++mt)
        #pragma unroll
        for (int kt = 0; kt < 2; ++kt)
            wf[mt][kt] = *(const short8*)(Wproj + (mt * 16 + l15) * 64 + kt * 32 + l4 * 8);
    float bias[3][4];
    #pragma unroll
    for (int mt = 0; mt < 3; ++mt)
        #pragma unroll
        for (int q = 0; q < 4; ++q)
            bias[mt][q] = cbias[mt * 16 + l4 * 4 + q];

    // ---- compute: wave owns positions [wid*64, wid*64+64)
    #pragma unroll 1
    for (int nt = 0; nt < 4; ++nt) {
        int lp = wid * 64 + nt * 16 + l15;         // local position
        u32 p = (u32)(pblk0 + lp);                 // global position
        short8 bfrag[2];
        #pragma unroll
        for (int kt = 0; kt < 2; ++kt) {
            int ch0 = kt * 32 + l4 * 8;
            short8 s;
            #pragma unroll
            for (int e = 0; e < 8; ++e) s[e] = (short)ldsA[ch0 + e][lp];
            bfrag[kt] = s;
        }
        f32x4 acc[3];
        #pragma unroll
        for (int mt = 0; mt < 3; ++mt) {
            f32x4 a = {bias[mt][0], bias[mt][1], bias[mt][2], bias[mt][3]};
            acc[mt] = a;
        }
        #pragma unroll
        for (int kt = 0; kt < 2; ++kt)
            #pragma unroll
            for (int mt = 0; mt < 3; ++mt)
                acc[mt] = MFMA16(wf[mt][kt], bfrag[kt], acc[mt]);
        // planar store: plane jd = 4*mt + l4 (valid jd < 10), 8B per pos
        #pragma unroll
        for (int mt = 0; mt < 3; ++mt) {
            if (mt == 2 && l4 >= 2) continue;
            uint2 st;
            st.x = packbf2(acc[mt][0], acc[mt][1]);
            st.y = packbf2(acc[mt][2], acc[mt][3]);
            *(uint2*)(proj + ((size_t)(4 * mt + l4) * NPOS + p) * 4) = st;
        }
    }
}

// ================= fused: f1 = relu(X@W1+b1); S^T = Wbot.f1^T + gather(proj) =
__global__ __launch_bounds__(256) void fused2_kernel(const float* __restrict__ fusion,
        const int* __restrict__ idx, const float* __restrict__ b1,
        const u16* __restrict__ W1t, const u16* __restrict__ Wbot,
        const u16* __restrict__ proj, float* __restrict__ out) {
    __shared__ __align__(16) u32 sbuf[4][16][44];   // per-wave rows: f1 relayout then output staging
    int tid = threadIdx.x;
    int lane = tid & 63, wid = tid >> 6;
    int l15 = lane & 15, l4 = lane >> 4;
    int t = blockIdx.x * 4 + wid;                   // wave id; 7500 waves exactly
    int i0 = t * 32;

    short8 w1f[4][3];
    #pragma unroll
    for (int mt = 0; mt < 4; ++mt)
        #pragma unroll
        for (int kt = 0; kt < 3; ++kt)
            w1f[mt][kt] = *(const short8*)(W1t + (mt * 16 + l15) * 96 + kt * 32 + l4 * 8);
    short8 wbf[2][2];
    #pragma unroll
    for (int mt = 0; mt < 2; ++mt)
        #pragma unroll
        for (int kt = 0; kt < 2; ++kt)
            wbf[mt][kt] = *(const short8*)(Wbot + (mt * 16 + l15) * 64 + kt * 32 + l4 * 8);
    float b1r[4][4];
    #pragma unroll
    for (int mt = 0; mt < 4; ++mt)
        #pragma unroll
        for (int q = 0; q < 4; ++q)
            b1r[mt][q] = b1[mt * 16 + l4 * 4 + q];

    u32* myl = &sbuf[wid][0][0];
    #pragma unroll 1
    for (int nt = 0; nt < 2; ++nt) {
        int ipb = i0 + nt * 16;
        int ip = ipb + l15;                         // this lane's column point
        u64 hv = __builtin_nontemporal_load((const u64*)idx + ip);
        u32 hh = (u32)hv, ww = (u32)(hv >> 32);
        size_t pos = ((size_t)(u32)(ip / NPTS) * 376 + hh) * 376 + ww;
        f32x4 acc[3];
        #pragma unroll
        for (int mt = 0; mt < 3; ++mt) {
            if (mt == 2 && l4 >= 2) { f32x4 z = {0.f, 0.f, 0.f, 0.f}; acc[mt] = z; }
            else {
                uint2 v = *(const uint2*)(proj + ((size_t)(4 * mt + l4) * NPOS + pos) * 4);
                f32x4 a = {bf2f(v.x & 0xffffu), bf2f(v.x >> 16),
                           bf2f(v.y & 0xffffu), bf2f(v.y >> 16)};
                acc[mt] = a;
            }
        }
        // GEMM1: C1^T[c][pos] = W1t . X^T
        const float* frow = fusion + (size_t)ip * NDIN;
        f32x4 c1[4];
        #pragma unroll
        for (int mt = 0; mt < 4; ++mt) {
            f32x4 a = {b1r[mt][0], b1r[mt][1], b1r[mt][2], b1r[mt][3]};
            c1[mt] = a;
        }
        #pragma unroll
        for (int kt = 0; kt < 3; ++kt) {
            short8 xf = {0, 0, 0, 0, 0, 0, 0, 0};
            int d0 = kt * 32 + l4 * 8;
            if (d0 < 80) {
                fv4 a = __builtin_nontemporal_load((const fv4*)(frow + d0));
                fv4 bq = __builtin_nontemporal_load((const fv4*)(frow + d0 + 4));
                short8 s;
                s[0] = (short)f2bf(a.x);  s[1] = (short)f2bf(a.y);
                s[2] = (short)f2bf(a.z);  s[3] = (short)f2bf(a.w);
                s[4] = (short)f2bf(bq.x); s[5] = (short)f2bf(bq.y);
                s[6] = (short)f2bf(bq.z); s[7] = (short)f2bf(bq.w);
                xf = s;
            }
            #pragma unroll
            for (int mt = 0; mt < 4; ++mt) c1[mt] = MFMA16(w1f[mt][kt], xf, c1[mt]);
        }
        // relu -> bf16 -> swizzled LDS [pos][c] (rows stride 44 words)
        #pragma unroll
        for (int mt = 0; mt < 4; ++mt) {
            float x0 = fmaxf(c1[mt][0], 0.f), x1 = fmaxf(c1[mt][1], 0.f);
            float x2 = fmaxf(c1[mt][2], 0.f), x3 = fmaxf(c1[mt][3], 0.f);
            u32 lo = packbf2(x0, x1), hi = packbf2(x2, x3);
            int c0 = mt * 16 + l4 * 4;
            int gsw = (c0 >> 3) ^ (l15 & 7);
            *(u64*)(myl + l15 * 44 + gsw * 4 + ((c0 & 4) >> 1)) = (u64)lo | ((u64)hi << 32);
        }
        // GEMM2: S^T += Wbot . f1^T
        #pragma unroll
        for (int kt = 0; kt < 2; ++kt) {
            int gsw = (kt * 4 + l4) ^ (l15 & 7);
            short8 f1f = *(const short8*)(myl + l15 * 44 + gsw * 4);
            #pragma unroll
            for (int mt = 0; mt < 2; ++mt) acc[mt] = MFMA16(wbf[mt][kt], f1f, acc[mt]);
        }
        // stage outputs to LDS rows (overwrites f1 region; same-wave in-order DS)
        #pragma unroll
        for (int mt = 0; mt < 3; ++mt) {
            if (mt == 2 && l4 >= 2) continue;
            *(f32x4*)(myl + l15 * 44 + mt * 16 + l4 * 4) = acc[mt];
        }
        // cooperative coalesced write: 16 rows x 19 floats per head
        size_t o1 = (size_t)ipb * 19;
        #pragma unroll
        for (int s = 0; s < 5; ++s) {
            int f = lane + s * 64;
            if (f < 304) {
                u32 rr = (u32)f / 19u;
                u32 jj = (u32)f - rr * 19u;
                float v1 = __builtin_bit_cast(float, myl[rr * 44 + jj]);
                float v2 = __builtin_bit_cast(float, myl[rr * 44 + 20 + jj]);
                __builtin_nontemporal_store(v1, out + o1 + f);
                __builtin_nontemporal_store(v2, out + (size_t)NTOTP * 19 + o1 + f);
            }
        }
    }
}

// ================= fallback (tiny ws): direct path ==========================
__global__ void precompute_old(const float* __restrict__ W2, const float* __restrict__ b2,
                               const float* __restrict__ Wc1, const float* __restrict__ bc1,
                               float* __restrict__ wsA, float* __restrict__ wsc1) {
    int t = blockIdx.x * 256 + threadIdx.x;
    if (t < 128 * 20) {
        int k = t / 20, j = t % 20;
        float v = 0.f;
        if (j < 19) for (int c = 0; c < 64; ++c) v += W2[k * 64 + c] * Wc1[c * 19 + j];
        wsA[t] = v;
    } else if (t < 128 * 20 + 20) {
        int j = t - 128 * 20;
        float v = 0.f;
        if (j < 19) { v = bc1[j]; for (int c = 0; c < 64; ++c) v += b2[c] * Wc1[c * 19 + j]; }
        wsc1[j] = v;
    }
}

__device__ __forceinline__ void fma4o(float4& a, float s, const float4 b) {
    a.x = fmaf(s, b.x, a.x); a.y = fmaf(s, b.y, a.y);
    a.z = fmaf(s, b.z, a.z); a.w = fmaf(s, b.w, a.w);
}

__global__ __launch_bounds__(256) void fused_old(
    const float* __restrict__ feats, const float* __restrict__ fusion,
    const int* __restrict__ idx, const float* __restrict__ W1, const float* __restrict__ b1,
    const float* __restrict__ Wc2, const float* __restrict__ bc2,
    const float* __restrict__ wsA, const float* __restrict__ wsc1, float* __restrict__ out) {
    __shared__ __align__(16) float sW1[80 * 64];
    __shared__ __align__(16) float sA[128 * 20];
    __shared__ __align__(16) float sWc2[64 * 20];
    __shared__ __align__(16) float sb1[64];
    __shared__ __align__(16) float sc1[20];
    __shared__ __align__(16) float sbc2[20];
    int tid = threadIdx.x;
    for (int t = tid; t < 80 * 64; t += 256) sW1[t] = W1[t];
    for (int t = tid; t < 128 * 20; t += 256) sA[t] = wsA[t];
    for (int t = tid; t < 64 * 20; t += 256) {
        int k = t / 20, j = t % 20;
        sWc2[t] = (j < 19) ? Wc2[k * 19 + j] : 0.f;
    }
    if (tid < 64) sb1[tid] = b1[tid];
    if (tid < 20) sc1[tid] = wsc1[tid];
    if (tid < 20) sbc2[tid] = (tid < 19) ? bc2[tid] : 0.f;
    __syncthreads();
    int i0 = blockIdx.x * 256 + tid;
    bool act = (i0 < NTOTP);
    int i = act ? i0 : 0;
    int b = i / NPTS;
    int2 hw = ((const int2*)idx)[i];
    float4 f14[16];
    #pragma unroll
    for (int c4 = 0; c4 < 16; ++c4) f14[c4] = ((const float4*)sb1)[c4];
    const float4* fu4 = (const float4*)(fusion + (size_t)i * NDIN);
    for (int d4 = 0; d4 < NDIN / 4; ++d4) {
        float4 x = fu4[d4];
        const float* wr = sW1 + d4 * 256;
        #pragma unroll
        for (int c4 = 0; c4 < 16; ++c4) {
            fma4o(f14[c4], x.x, *(const float4*)(wr + c4 * 4));
            fma4o(f14[c4], x.y, *(const float4*)(wr + 64 + c4 * 4));
            fma4o(f14[c4], x.z, *(const float4*)(wr + 128 + c4 * 4));
            fma4o(f14[c4], x.w, *(const float4*)(wr + 192 + c4 * 4));
        }
    }
    #pragma unroll
    for (int c4 = 0; c4 < 16; ++c4) {
        f14[c4].x = fmaxf(f14[c4].x, 0.f); f14[c4].y = fmaxf(f14[c4].y, 0.f);
        f14[c4].z = fmaxf(f14[c4].z, 0.f); f14[c4].w = fmaxf(f14[c4].w, 0.f);
    }
    float4 s14[5], s24[5];
    #pragma unroll
    for (int j4 = 0; j4 < 5; ++j4) { s14[j4] = ((const float4*)sc1)[j4]; s24[j4] = ((const float4*)sbc2)[j4]; }
    const float* fb = feats + (size_t)b * CHW_ + (size_t)hw.x * NWID + hw.y;
    for (int k = 0; k < 64; ++k) {
        float g = fb[(size_t)k * HW_];
        const float4* ar = (const float4*)(sA + k * 20);
        const float4* cr = (const float4*)(sWc2 + k * 20);
        #pragma unroll
        for (int j4 = 0; j4 < 5; ++j4) { fma4o(s14[j4], g, ar[j4]); fma4o(s24[j4], g, cr[j4]); }
    }
    const float* f1s = (const float*)f14;
    for (int k = 0; k < 64; ++k) {
        float g = f1s[k];
        const float4* ar = (const float4*)(sA + (64 + k) * 20);
        #pragma unroll
        for (int j4 = 0; j4 < 5; ++j4) fma4o(s14[j4], g, ar[j4]);
    }
    if (act) {
        float* o1 = out + (size_t)i * 19;
        float* o2 = out + (size_t)NTOTP * 19 + (size_t)i * 19;
        const float* s1s = (const float*)s14;
        const float* s2s = (const float*)s24;
        #pragma unroll
        for (int j = 0; j < 19; ++j) o1[j] = s1s[j];
        #pragma unroll
        for (int j = 0; j < 19; ++j) o2[j] = s2s[j];
    }
}

// ================= launch ====================================================
extern "C" void kernel_launch(void* const* d_in, const int* in_sizes, int n_in,
                              void* d_out, int out_size, void* d_ws, size_t ws_size,
                              hipStream_t stream) {
    const float* feats  = (const float*)d_in[0];
    const float* fusion = (const float*)d_in[1];
    const int*   idx    = (const int*)d_in[2];
    const float* W1  = (const float*)d_in[3];
    const float* b1  = (const float*)d_in[4];
    const float* W2  = (const float*)d_in[5];
    const float* b2  = (const float*)d_in[6];
    const float* Wc1 = (const float*)d_in[7];
    const float* bc1 = (const float*)d_in[8];
    const float* Wc2 = (const float*)d_in[9];
    const float* bc2 = (const float*)d_in[10];
    float* out = (float*)d_out;
    char* ws = (char*)d_ws;

    if (ws_size >= WS_NEED) {
        u16*   Wproj = (u16*)(ws + OFF_WPROJ);
        u16*   W1t   = (u16*)(ws + OFF_W1T);
        u16*   Wbot  = (u16*)(ws + OFF_WBOT);
        float* cbias = (float*)(ws + OFF_CBIAS);
        u16*   proj  = (u16*)(ws + OFF_PROJ);
        prep_kernel<<<45, 256, 0, stream>>>(W1, W2, b2, Wc1, bc1, Wc2, bc2,
                                            Wproj, W1t, Wbot, cbias);
        proj_kernel<<<NPOS / 256, 256, 0, stream>>>(feats, Wproj, cbias, proj);
        fused2_kernel<<<NTOTP / 128, 256, 0, stream>>>(fusion, idx, b1,
                                                       W1t, Wbot, proj, out);
    } else {
        float* wsA  = (float*)ws;
        float* wsc1 = wsA + 128 * 20;
        precompute_old<<<11, 256, 0, stream>>>(W2, b2, Wc1, bc1, wsA, wsc1);
        fused_old<<<(NTOTP + 255) / 256, 256, 0, stream>>>(feats, fusion, idx, W1, b1,
                                                           Wc2, bc2, wsA, wsc1, out);
    }
}

// Round 5
// 134.225 us; speedup vs baseline: 1.9632x; 1.2605x over previous
//
#include <hip/hip_runtime.h>

typedef unsigned int u32;
typedef unsigned short u16;
typedef unsigned long long u64;
typedef __attribute__((ext_vector_type(8))) short short8;
typedef __attribute__((ext_vector_type(4))) float f32x4;
typedef __attribute__((ext_vector_type(4))) float fv4;

#define NB 8
#define NC 64
#define NH 376
#define NWID 1241
#define NPTS 30000
#define NDIN 80
#define NTOTP 240000
#define PPB 141376              // 376*376 positions per sample
#define NPOS 1131008            // 8*PPB  (multiple of 256)
#define HW_ ((size_t)NH*NWID)
#define CHW_ ((size_t)NC*HW_)

// workspace layout (new path)
#define OFF_WPROJ 0             // u16[48*64]
#define OFF_W1T   8192          // u16[64*96]
#define OFF_WBOT  24576         // u16[32*64]
#define OFF_CBIAS 28672         // float[48]
#define OFF_PROJ  32768         // u16[NPOS][40]  (80B row per position)
#define WS_NEED   ((size_t)32768 + (size_t)NPOS*40*2)

__device__ __forceinline__ u16 f2bf(float f) {
    u32 u = __builtin_bit_cast(u32, f);
    return (u16)((u + 0x7FFFu + ((u >> 16) & 1u)) >> 16);
}
__device__ __forceinline__ float bf2f(u32 lo16) {
    return __builtin_bit_cast(float, lo16 << 16);
}
__device__ __forceinline__ u32 packbf2(float a, float b) {
    return (u32)f2bf(a) | ((u32)f2bf(b) << 16);
}
#define MFMA16(a,b,c) __builtin_amdgcn_mfma_f32_16x16x32_bf16(a, b, c, 0, 0, 0)

// ================= prep: build bf16 weight tables + folded biases ===========
__global__ void prep_kernel(const float* __restrict__ W1, const float* __restrict__ W2,
                            const float* __restrict__ b2, const float* __restrict__ Wc1,
                            const float* __restrict__ bc1, const float* __restrict__ Wc2,
                            const float* __restrict__ bc2,
                            u16* __restrict__ Wproj, u16* __restrict__ W1t,
                            u16* __restrict__ Wbot, float* __restrict__ cbias) {
    int t = blockIdx.x * 256 + threadIdx.x;
    if (t < 3072) {
        int j = t >> 6, ch = t & 63;
        float v = 0.f;
        if (j < 19) { for (int c = 0; c < 64; ++c) v += W2[ch * 64 + c] * Wc1[c * 19 + j]; }
        else if (j >= 20 && j < 39) v = Wc2[ch * 19 + (j - 20)];
        Wproj[t] = f2bf(v);
    } else if (t < 3072 + 6144) {
        int q = t - 3072; int c = q / 96, d = q % 96;
        W1t[q] = f2bf(d < 80 ? W1[d * 64 + c] : 0.f);
    } else if (t < 3072 + 6144 + 2048) {
        int q = t - 9216; int j = q >> 6, c = q & 63;
        float v = 0.f;
        if (j < 19) { for (int cc = 0; cc < 64; ++cc) v += W2[(64 + c) * 64 + cc] * Wc1[cc * 19 + j]; }
        Wbot[q] = f2bf(v);
    } else if (t < 3072 + 6144 + 2048 + 48) {
        int j = t - 11264;
        float v = 0.f;
        if (j < 19) { v = bc1[j]; for (int c = 0; c < 64; ++c) v += b2[c] * Wc1[c * 19 + j]; }
        else if (j >= 20 && j < 39) v = bc2[j - 20];
        cbias[j] = v;
    }
}

// ================= projection: block stages [64ch][256pos] in LDS ===========
// Stage loop unrolled x4 -> 16 loads/wave in flight (MLP vs DRAM activation).
// Output: proj[pos][40] bf16 rows, staged in LDS, written 256B-coalesced.
__global__ __launch_bounds__(256) void proj_kernel(const float* __restrict__ feats,
        const u16* __restrict__ Wproj, const float* __restrict__ cbias,
        u16* __restrict__ proj) {
    __shared__ __align__(16) u16 ldsA[64][264];   // 33.8 KB
    __shared__ __align__(16) u32 sst[4][16][20];  // 5 KB per-wave output staging
    int tid = threadIdx.x;
    int lane = tid & 63, wid = tid >> 6;
    int l15 = lane & 15, l4 = lane >> 4;
    int pblk0 = blockIdx.x * 256;

    // ---- stage: 16 channels per wave, 256 positions, 4B loads in dense runs
    {
        u32 p0 = (u32)(pblk0 + lane * 4);
        u32 b = p0 / PPB;                 // float4-span never crosses b/h (PPB%4==0, 376%4==0)
        u32 r = p0 - b * PPB;
        u32 h = r / 376u, w = r - h * 376u;
        const float* base0 = feats + (size_t)b * CHW_ + (size_t)h * NWID + w;
        #pragma unroll 4
        for (int it = 0; it < 16; ++it) {
            int c = wid * 16 + it;
            const float* src = base0 + (size_t)c * HW_;
            float v0 = __builtin_nontemporal_load(src + 0);
            float v1 = __builtin_nontemporal_load(src + 1);
            float v2 = __builtin_nontemporal_load(src + 2);
            float v3 = __builtin_nontemporal_load(src + 3);
            u64 pk = (u64)packbf2(v0, v1) | ((u64)packbf2(v2, v3) << 32);
            *(u64*)&ldsA[c][lane * 4] = pk;
        }
    }
    __syncthreads();

    // ---- weight fragments + bias
    short8 wf[3][2];
    #pragma unroll
    for (int mt = 0; mt < 3; ++mt)
        #pragma unroll
        for (int kt = 0; kt < 2; ++kt)
            wf[mt][kt] = *(const short8*)(Wproj + (mt * 16 + l15) * 64 + kt * 32 + l4 * 8);
    float bias[3][4];
    #pragma unroll
    for (int mt = 0; mt < 3; ++mt)
        #pragma unroll
        for (int q = 0; q < 4; ++q)
            bias[mt][q] = cbias[mt * 16 + l4 * 4 + q];

    // ---- compute: wave owns positions [wid*64, wid*64+64)
    #pragma unroll 1
    for (int nt = 0; nt < 4; ++nt) {
        int lp = wid * 64 + nt * 16 + l15;         // local position (this lane's column)
        short8 bfrag[2];
        #pragma unroll
        for (int kt = 0; kt < 2; ++kt) {
            int ch0 = kt * 32 + l4 * 8;
            short8 s;
            #pragma unroll
            for (int e = 0; e < 8; ++e) s[e] = (short)ldsA[ch0 + e][lp];
            bfrag[kt] = s;
        }
        f32x4 acc[3];
        #pragma unroll
        for (int mt = 0; mt < 3; ++mt) {
            f32x4 a = {bias[mt][0], bias[mt][1], bias[mt][2], bias[mt][3]};
            acc[mt] = a;
        }
        #pragma unroll
        for (int kt = 0; kt < 2; ++kt)
            #pragma unroll
            for (int mt = 0; mt < 3; ++mt)
                acc[mt] = MFMA16(wf[mt][kt], bfrag[kt], acc[mt]);
        // stage row slices into per-wave LDS: row l15, word mt*8+l4*2
        #pragma unroll
        for (int mt = 0; mt < 3; ++mt) {
            if (mt == 2 && l4 >= 2) continue;
            uint2 st;
            st.x = packbf2(acc[mt][0], acc[mt][1]);
            st.y = packbf2(acc[mt][2], acc[mt][3]);
            *(uint2*)&sst[wid][l15][mt * 8 + l4 * 2] = st;
        }
        // cooperative coalesced store: 16 rows x 80B = 1280B contiguous
        const u32* s0 = &sst[wid][0][0];
        u32* dst = (u32*)(proj + (size_t)(pblk0 + wid * 64 + nt * 16) * 40);
        #pragma unroll
        for (int s = 0; s < 5; ++s) dst[lane + s * 64] = s0[lane + s * 64];
    }
}

// ================= fused: f1 = relu(X@W1+b1); S^T = Wbot.f1^T + gather(proj) =
__global__ __launch_bounds__(256) void fused2_kernel(const float* __restrict__ fusion,
        const int* __restrict__ idx, const float* __restrict__ b1,
        const u16* __restrict__ W1t, const u16* __restrict__ Wbot,
        const u16* __restrict__ proj, float* __restrict__ out) {
    __shared__ __align__(16) u32 sbuf[4][16][44];   // per-wave rows: f1 relayout then output staging
    int tid = threadIdx.x;
    int lane = tid & 63, wid = tid >> 6;
    int l15 = lane & 15, l4 = lane >> 4;
    int t = blockIdx.x * 4 + wid;                   // wave id; 7500 waves exactly
    int i0 = t * 32;

    short8 w1f[4][3];
    #pragma unroll
    for (int mt = 0; mt < 4; ++mt)
        #pragma unroll
        for (int kt = 0; kt < 3; ++kt)
            w1f[mt][kt] = *(const short8*)(W1t + (mt * 16 + l15) * 96 + kt * 32 + l4 * 8);
    short8 wbf[2][2];
    #pragma unroll
    for (int mt = 0; mt < 2; ++mt)
        #pragma unroll
        for (int kt = 0; kt < 2; ++kt)
            wbf[mt][kt] = *(const short8*)(Wbot + (mt * 16 + l15) * 64 + kt * 32 + l4 * 8);
    float b1r[4][4];
    #pragma unroll
    for (int mt = 0; mt < 4; ++mt)
        #pragma unroll
        for (int q = 0; q < 4; ++q)
            b1r[mt][q] = b1[mt * 16 + l4 * 4 + q];

    u32* myl = &sbuf[wid][0][0];
    #pragma unroll 1
    for (int nt = 0; nt < 2; ++nt) {
        int ipb = i0 + nt * 16;
        int ip = ipb + l15;                         // this lane's column point
        u64 hv = __builtin_nontemporal_load((const u64*)idx + ip);
        u32 hh = (u32)hv, ww = (u32)(hv >> 32);
        size_t pos = ((size_t)(u32)(ip / NPTS) * 376 + hh) * 376 + ww;
        const u16* prow = proj + pos * 40;
        f32x4 acc[3];
        #pragma unroll
        for (int mt = 0; mt < 3; ++mt) {
            if (mt == 2 && l4 >= 2) { f32x4 z = {0.f, 0.f, 0.f, 0.f}; acc[mt] = z; }
            else {
                uint2 v = *(const uint2*)(prow + mt * 16 + l4 * 4);
                f32x4 a = {bf2f(v.x & 0xffffu), bf2f(v.x >> 16),
                           bf2f(v.y & 0xffffu), bf2f(v.y >> 16)};
                acc[mt] = a;
            }
        }
        // GEMM1: C1^T[c][pos] = W1t . X^T
        const float* frow = fusion + (size_t)ip * NDIN;
        f32x4 c1[4];
        #pragma unroll
        for (int mt = 0; mt < 4; ++mt) {
            f32x4 a = {b1r[mt][0], b1r[mt][1], b1r[mt][2], b1r[mt][3]};
            c1[mt] = a;
        }
        #pragma unroll
        for (int kt = 0; kt < 3; ++kt) {
            short8 xf = {0, 0, 0, 0, 0, 0, 0, 0};
            int d0 = kt * 32 + l4 * 8;
            if (d0 < 80) {
                fv4 a = __builtin_nontemporal_load((const fv4*)(frow + d0));
                fv4 bq = __builtin_nontemporal_load((const fv4*)(frow + d0 + 4));
                short8 s;
                s[0] = (short)f2bf(a.x);  s[1] = (short)f2bf(a.y);
                s[2] = (short)f2bf(a.z);  s[3] = (short)f2bf(a.w);
                s[4] = (short)f2bf(bq.x); s[5] = (short)f2bf(bq.y);
                s[6] = (short)f2bf(bq.z); s[7] = (short)f2bf(bq.w);
                xf = s;
            }
            #pragma unroll
            for (int mt = 0; mt < 4; ++mt) c1[mt] = MFMA16(w1f[mt][kt], xf, c1[mt]);
        }
        // relu -> bf16 -> swizzled LDS [pos][c] (rows stride 44 words)
        #pragma unroll
        for (int mt = 0; mt < 4; ++mt) {
            float x0 = fmaxf(c1[mt][0], 0.f), x1 = fmaxf(c1[mt][1], 0.f);
            float x2 = fmaxf(c1[mt][2], 0.f), x3 = fmaxf(c1[mt][3], 0.f);
            u32 lo = packbf2(x0, x1), hi = packbf2(x2, x3);
            int c0 = mt * 16 + l4 * 4;
            int gsw = (c0 >> 3) ^ (l15 & 7);
            *(u64*)(myl + l15 * 44 + gsw * 4 + ((c0 & 4) >> 1)) = (u64)lo | ((u64)hi << 32);
        }
        // GEMM2: S^T += Wbot . f1^T
        #pragma unroll
        for (int kt = 0; kt < 2; ++kt) {
            int gsw = (kt * 4 + l4) ^ (l15 & 7);
            short8 f1f = *(const short8*)(myl + l15 * 44 + gsw * 4);
            #pragma unroll
            for (int mt = 0; mt < 2; ++mt) acc[mt] = MFMA16(wbf[mt][kt], f1f, acc[mt]);
        }
        // stage outputs to LDS rows (overwrites f1 region; same-wave in-order DS)
        #pragma unroll
        for (int mt = 0; mt < 3; ++mt) {
            if (mt == 2 && l4 >= 2) continue;
            *(f32x4*)(myl + l15 * 44 + mt * 16 + l4 * 4) = acc[mt];
        }
        // cooperative coalesced write: 16 rows x 19 floats per head
        size_t o1 = (size_t)ipb * 19;
        #pragma unroll
        for (int s = 0; s < 5; ++s) {
            int f = lane + s * 64;
            if (f < 304) {
                u32 rr = (u32)f / 19u;
                u32 jj = (u32)f - rr * 19u;
                float v1 = __builtin_bit_cast(float, myl[rr * 44 + jj]);
                float v2 = __builtin_bit_cast(float, myl[rr * 44 + 20 + jj]);
                __builtin_nontemporal_store(v1, out + o1 + f);
                __builtin_nontemporal_store(v2, out + (size_t)NTOTP * 19 + o1 + f);
            }
        }
    }
}

// ================= fallback (tiny ws): direct path ==========================
__global__ void precompute_old(const float* __restrict__ W2, const float* __restrict__ b2,
                               const float* __restrict__ Wc1, const float* __restrict__ bc1,
                               float* __restrict__ wsA, float* __restrict__ wsc1) {
    int t = blockIdx.x * 256 + threadIdx.x;
    if (t < 128 * 20) {
        int k = t / 20, j = t % 20;
        float v = 0.f;
        if (j < 19) for (int c = 0; c < 64; ++c) v += W2[k * 64 + c] * Wc1[c * 19 + j];
        wsA[t] = v;
    } else if (t < 128 * 20 + 20) {
        int j = t - 128 * 20;
        float v = 0.f;
        if (j < 19) { v = bc1[j]; for (int c = 0; c < 64; ++c) v += b2[c] * Wc1[c * 19 + j]; }
        wsc1[j] = v;
    }
}

__device__ __forceinline__ void fma4o(float4& a, float s, const float4 b) {
    a.x = fmaf(s, b.x, a.x); a.y = fmaf(s, b.y, a.y);
    a.z = fmaf(s, b.z, a.z); a.w = fmaf(s, b.w, a.w);
}

__global__ __launch_bounds__(256) void fused_old(
    const float* __restrict__ feats, const float* __restrict__ fusion,
    const int* __restrict__ idx, const float* __restrict__ W1, const float* __restrict__ b1,
    const float* __restrict__ Wc2, const float* __restrict__ bc2,
    const float* __restrict__ wsA, const float* __restrict__ wsc1, float* __restrict__ out) {
    __shared__ __align__(16) float sW1[80 * 64];
    __shared__ __align__(16) float sA[128 * 20];
    __shared__ __align__(16) float sWc2[64 * 20];
    __shared__ __align__(16) float sb1[64];
    __shared__ __align__(16) float sc1[20];
    __shared__ __align__(16) float sbc2[20];
    int tid = threadIdx.x;
    for (int t = tid; t < 80 * 64; t += 256) sW1[t] = W1[t];
    for (int t = tid; t < 128 * 20; t += 256) sA[t] = wsA[t];
    for (int t = tid; t < 64 * 20; t += 256) {
        int k = t / 20, j = t % 20;
        sWc2[t] = (j < 19) ? Wc2[k * 19 + j] : 0.f;
    }
    if (tid < 64) sb1[tid] = b1[tid];
    if (tid < 20) sc1[tid] = wsc1[tid];
    if (tid < 20) sbc2[tid] = (tid < 19) ? bc2[tid] : 0.f;
    __syncthreads();
    int i0 = blockIdx.x * 256 + tid;
    bool act = (i0 < NTOTP);
    int i = act ? i0 : 0;
    int b = i / NPTS;
    int2 hw = ((const int2*)idx)[i];
    float4 f14[16];
    #pragma unroll
    for (int c4 = 0; c4 < 16; ++c4) f14[c4] = ((const float4*)sb1)[c4];
    const float4* fu4 = (const float4*)(fusion + (size_t)i * NDIN);
    for (int d4 = 0; d4 < NDIN / 4; ++d4) {
        float4 x = fu4[d4];
        const float* wr = sW1 + d4 * 256;
        #pragma unroll
        for (int c4 = 0; c4 < 16; ++c4) {
            fma4o(f14[c4], x.x, *(const float4*)(wr + c4 * 4));
            fma4o(f14[c4], x.y, *(const float4*)(wr + 64 + c4 * 4));
            fma4o(f14[c4], x.z, *(const float4*)(wr + 128 + c4 * 4));
            fma4o(f14[c4], x.w, *(const float4*)(wr + 192 + c4 * 4));
        }
    }
    #pragma unroll
    for (int c4 = 0; c4 < 16; ++c4) {
        f14[c4].x = fmaxf(f14[c4].x, 0.f); f14[c4].y = fmaxf(f14[c4].y, 0.f);
        f14[c4].z = fmaxf(f14[c4].z, 0.f); f14[c4].w = fmaxf(f14[c4].w, 0.f);
    }
    float4 s14[5], s24[5];
    #pragma unroll
    for (int j4 = 0; j4 < 5; ++j4) { s14[j4] = ((const float4*)sc1)[j4]; s24[j4] = ((const float4*)sbc2)[j4]; }
    const float* fb = feats + (size_t)b * CHW_ + (size_t)hw.x * NWID + hw.y;
    for (int k = 0; k < 64; ++k) {
        float g = fb[(size_t)k * HW_];
        const float4* ar = (const float4*)(sA + k * 20);
        const float4* cr = (const float4*)(sWc2 + k * 20);
        #pragma unroll
        for (int j4 = 0; j4 < 5; ++j4) { fma4o(s14[j4], g, ar[j4]); fma4o(s24[j4], g, cr[j4]); }
    }
    const float* f1s = (const float*)f14;
    for (int k = 0; k < 64; ++k) {
        float g = f1s[k];
        const float4* ar = (const float4*)(sA + (64 + k) * 20);
        #pragma unroll
        for (int j4 = 0; j4 < 5; ++j4) fma4o(s14[j4], g, ar[j4]);
    }
    if (act) {
        float* o1 = out + (size_t)i * 19;
        float* o2 = out + (size_t)NTOTP * 19 + (size_t)i * 19;
        const float* s1s = (const float*)s14;
        const float* s2s = (const float*)s24;
        #pragma unroll
        for (int j = 0; j < 19; ++j) o1[j] = s1s[j];
        #pragma unroll
        for (int j = 0; j < 19; ++j) o2[j] = s2s[j];
    }
}

// ================= launch ====================================================
extern "C" void kernel_launch(void* const* d_in, const int* in_sizes, int n_in,
                              void* d_out, int out_size, void* d_ws, size_t ws_size,
                              hipStream_t stream) {
    const float* feats  = (const float*)d_in[0];
    const float* fusion = (const float*)d_in[1];
    const int*   idx    = (const int*)d_in[2];
    const float* W1  = (const float*)d_in[3];
    const float* b1  = (const float*)d_in[4];
    const float* W2  = (const float*)d_in[5];
    const float* b2  = (const float*)d_in[6];
    const float* Wc1 = (const float*)d_in[7];
    const float* bc1 = (const float*)d_in[8];
    const float* Wc2 = (const float*)d_in[9];
    const float* bc2 = (const float*)d_in[10];
    float* out = (float*)d_out;
    char* ws = (char*)d_ws;

    if (ws_size >= WS_NEED) {
        u16*   Wproj = (u16*)(ws + OFF_WPROJ);
        u16*   W1t   = (u16*)(ws + OFF_W1T);
        u16*   Wbot  = (u16*)(ws + OFF_WBOT);
        float* cbias = (float*)(ws + OFF_CBIAS);
        u16*   proj  = (u16*)(ws + OFF_PROJ);
        prep_kernel<<<45, 256, 0, stream>>>(W1, W2, b2, Wc1, bc1, Wc2, bc2,
                                            Wproj, W1t, Wbot, cbias);
        proj_kernel<<<NPOS / 256, 256, 0, stream>>>(feats, Wproj, cbias, proj);
        fused2_kernel<<<NTOTP / 128, 256, 0, stream>>>(fusion, idx, b1,
                                                       W1t, Wbot, proj, out);
    } else {
        float* wsA  = (float*)ws;
        float* wsc1 = wsA + 128 * 20;
        precompute_old<<<11, 256, 0, stream>>>(W2, b2, Wc1, bc1, wsA, wsc1);
        fused_old<<<(NTOTP + 255) / 256, 256, 0, stream>>>(feats, fusion, idx, W1, b1,
                                                           Wc2, bc2, wsA, wsc1, out);
    }
}

// Round 6
// 130.743 us; speedup vs baseline: 2.0155x; 1.0266x over previous
//
#include <hip/hip_runtime.h>

typedef unsigned int u32;
typedef unsigned short u16;
typedef unsigned long long u64;
typedef __attribute__((ext_vector_type(8))) short short8;
typedef __attribute__((ext_vector_type(4))) float f32x4;
typedef __attribute__((ext_vector_type(4))) float fv4;

#define NB 8
#define NC 64
#define NH 376
#define NWID 1241
#define NPTS 30000
#define NDIN 80
#define NTOTP 240000
#define PPB 141376              // 376*376 positions per sample
#define NPOS 1131008            // 8*PPB  (multiple of 256)
#define HW_ ((size_t)NH*NWID)
#define CHW_ ((size_t)NC*HW_)

// workspace layout (new path)
#define OFF_WPROJ 0             // u16[48*64]
#define OFF_W1T   8192          // u16[64*96]
#define OFF_WBOT  24576         // u16[32*64]
#define OFF_CBIAS 28672         // float[48]
#define OFF_PROJ  32768         // u16[NPOS][40]  (80B row per position)
#define WS_NEED   ((size_t)32768 + (size_t)NPOS*40*2)

__device__ __forceinline__ u16 f2bf(float f) {
    u32 u = __builtin_bit_cast(u32, f);
    return (u16)((u + 0x7FFFu + ((u >> 16) & 1u)) >> 16);
}
__device__ __forceinline__ float bf2f(u32 lo16) {
    return __builtin_bit_cast(float, lo16 << 16);
}
__device__ __forceinline__ u32 packbf2(float a, float b) {
    return (u32)f2bf(a) | ((u32)f2bf(b) << 16);
}
#define MFMA16(a,b,c) __builtin_amdgcn_mfma_f32_16x16x32_bf16(a, b, c, 0, 0, 0)

// ================= prep: build bf16 weight tables + folded biases ===========
__global__ void prep_kernel(const float* __restrict__ W1, const float* __restrict__ W2,
                            const float* __restrict__ b2, const float* __restrict__ Wc1,
                            const float* __restrict__ bc1, const float* __restrict__ Wc2,
                            const float* __restrict__ bc2,
                            u16* __restrict__ Wproj, u16* __restrict__ W1t,
                            u16* __restrict__ Wbot, float* __restrict__ cbias) {
    int t = blockIdx.x * 256 + threadIdx.x;
    if (t < 3072) {
        int j = t >> 6, ch = t & 63;
        float v = 0.f;
        if (j < 19) { for (int c = 0; c < 64; ++c) v += W2[ch * 64 + c] * Wc1[c * 19 + j]; }
        else if (j >= 20 && j < 39) v = Wc2[ch * 19 + (j - 20)];
        Wproj[t] = f2bf(v);
    } else if (t < 3072 + 6144) {
        int q = t - 3072; int c = q / 96, d = q % 96;
        W1t[q] = f2bf(d < 80 ? W1[d * 64 + c] : 0.f);
    } else if (t < 3072 + 6144 + 2048) {
        int q = t - 9216; int j = q >> 6, c = q & 63;
        float v = 0.f;
        if (j < 19) { for (int cc = 0; cc < 64; ++cc) v += W2[(64 + c) * 64 + cc] * Wc1[cc * 19 + j]; }
        Wbot[q] = f2bf(v);
    } else if (t < 3072 + 6144 + 2048 + 48) {
        int j = t - 11264;
        float v = 0.f;
        if (j < 19) { v = bc1[j]; for (int c = 0; c < 64; ++c) v += b2[c] * Wc1[c * 19 + j]; }
        else if (j >= 20 && j < 39) v = bc2[j - 20];
        cbias[j] = v;
    }
}

// ================= projection: block stages [64ch][256pos] in LDS ===========
// dwordx4 stage loads (1KB/instr coalescing), fully unrolled (16KB/wave in
// flight); bijective XCD swizzle so each XCD sweeps contiguous position space.
#define PROJ_NWG (NPOS / 256)   // 4418
__global__ __launch_bounds__(256) void proj_kernel(const float* __restrict__ feats,
        const u16* __restrict__ Wproj, const float* __restrict__ cbias,
        u16* __restrict__ proj) {
    __shared__ __align__(16) u16 ldsA[64][264];   // 33.8 KB
    __shared__ __align__(16) u32 sst[4][16][20];  // 5 KB per-wave output staging
    int tid = threadIdx.x;
    int lane = tid & 63, wid = tid >> 6;
    int l15 = lane & 15, l4 = lane >> 4;
    // bijective XCD-aware swizzle (m204): q=nwg/8, r=nwg%8
    int orig = blockIdx.x;
    {
        const int q = PROJ_NWG / 8, r = PROJ_NWG % 8;
        int xcd = orig & 7, lid = orig >> 3;
        orig = (xcd < r ? xcd * (q + 1) : r * (q + 1) + (xcd - r) * q) + lid;
    }
    int pblk0 = orig * 256;

    // ---- stage: 16 channels per wave, 256 positions, one dwordx4 per lane/ch
    {
        u32 p0 = (u32)(pblk0 + lane * 4);
        u32 b = p0 / PPB;                 // float4-span never crosses b/h (PPB%4==0, 376%4==0)
        u32 r = p0 - b * PPB;
        u32 h = r / 376u, w = r - h * 376u;
        const float* base0 = feats + (size_t)b * CHW_ + (size_t)h * NWID + w;
        #pragma unroll
        for (int it = 0; it < 16; ++it) {
            int c = wid * 16 + it;
            fv4 v = __builtin_nontemporal_load((const fv4*)(base0 + (size_t)c * HW_));
            u64 pk = (u64)packbf2(v.x, v.y) | ((u64)packbf2(v.z, v.w) << 32);
            *(u64*)&ldsA[c][lane * 4] = pk;
        }
    }
    __syncthreads();

    // ---- weight fragments + bias
    short8 wf[3][2];
    #pragma unroll
    for (int mt = 0; mt < 3; ++mt)
        #pragma unroll
        for (int kt = 0; kt < 2; ++kt)
            wf[mt][kt] = *(const short8*)(Wproj + (mt * 16 + l15) * 64 + kt * 32 + l4 * 8);
    float bias[3][4];
    #pragma unroll
    for (int mt = 0; mt < 3; ++mt)
        #pragma unroll
        for (int q = 0; q < 4; ++q)
            bias[mt][q] = cbias[mt * 16 + l4 * 4 + q];

    // ---- compute: wave owns positions [wid*64, wid*64+64)
    #pragma unroll 1
    for (int nt = 0; nt < 4; ++nt) {
        int lp = wid * 64 + nt * 16 + l15;         // local position (this lane's column)
        short8 bfrag[2];
        #pragma unroll
        for (int kt = 0; kt < 2; ++kt) {
            int ch0 = kt * 32 + l4 * 8;
            short8 s;
            #pragma unroll
            for (int e = 0; e < 8; ++e) s[e] = (short)ldsA[ch0 + e][lp];
            bfrag[kt] = s;
        }
        f32x4 acc[3];
        #pragma unroll
        for (int mt = 0; mt < 3; ++mt) {
            f32x4 a = {bias[mt][0], bias[mt][1], bias[mt][2], bias[mt][3]};
            acc[mt] = a;
        }
        #pragma unroll
        for (int kt = 0; kt < 2; ++kt)
            #pragma unroll
            for (int mt = 0; mt < 3; ++mt)
                acc[mt] = MFMA16(wf[mt][kt], bfrag[kt], acc[mt]);
        // stage row slices into per-wave LDS: row l15, word mt*8+l4*2
        #pragma unroll
        for (int mt = 0; mt < 3; ++mt) {
            if (mt == 2 && l4 >= 2) continue;
            uint2 st;
            st.x = packbf2(acc[mt][0], acc[mt][1]);
            st.y = packbf2(acc[mt][2], acc[mt][3]);
            *(uint2*)&sst[wid][l15][mt * 8 + l4 * 2] = st;
        }
        // cooperative coalesced store: 16 rows x 80B = 1280B contiguous
        const u32* s0 = &sst[wid][0][0];
        u32* dst = (u32*)(proj + (size_t)(pblk0 + wid * 64 + nt * 16) * 40);
        #pragma unroll
        for (int s = 0; s < 5; ++s) dst[lane + s * 64] = s0[lane + s * 64];
    }
}

// ================= fused: f1 = relu(X@W1+b1); S^T = Wbot.f1^T + gather(proj) =
__global__ __launch_bounds__(256) void fused2_kernel(const float* __restrict__ fusion,
        const int* __restrict__ idx, const float* __restrict__ b1,
        const u16* __restrict__ W1t, const u16* __restrict__ Wbot,
        const u16* __restrict__ proj, float* __restrict__ out) {
    __shared__ __align__(16) u32 sbuf[4][16][44];   // per-wave rows: f1 relayout then output staging
    int tid = threadIdx.x;
    int lane = tid & 63, wid = tid >> 6;
    int l15 = lane & 15, l4 = lane >> 4;
    int t = blockIdx.x * 4 + wid;                   // wave id; 7500 waves exactly
    int i0 = t * 32;

    short8 w1f[4][3];
    #pragma unroll
    for (int mt = 0; mt < 4; ++mt)
        #pragma unroll
        for (int kt = 0; kt < 3; ++kt)
            w1f[mt][kt] = *(const short8*)(W1t + (mt * 16 + l15) * 96 + kt * 32 + l4 * 8);
    short8 wbf[2][2];
    #pragma unroll
    for (int mt = 0; mt < 2; ++mt)
        #pragma unroll
        for (int kt = 0; kt < 2; ++kt)
            wbf[mt][kt] = *(const short8*)(Wbot + (mt * 16 + l15) * 64 + kt * 32 + l4 * 8);
    float b1r[4][4];
    #pragma unroll
    for (int mt = 0; mt < 4; ++mt)
        #pragma unroll
        for (int q = 0; q < 4; ++q)
            b1r[mt][q] = b1[mt * 16 + l4 * 4 + q];

    u32* myl = &sbuf[wid][0][0];
    #pragma unroll 1
    for (int nt = 0; nt < 2; ++nt) {
        int ipb = i0 + nt * 16;
        int ip = ipb + l15;                         // this lane's column point
        u64 hv = __builtin_nontemporal_load((const u64*)idx + ip);
        u32 hh = (u32)hv, ww = (u32)(hv >> 32);
        size_t pos = ((size_t)(u32)(ip / NPTS) * 376 + hh) * 376 + ww;
        const u16* prow = proj + pos * 40;
        f32x4 acc[3];
        #pragma unroll
        for (int mt = 0; mt < 3; ++mt) {
            if (mt == 2 && l4 >= 2) { f32x4 z = {0.f, 0.f, 0.f, 0.f}; acc[mt] = z; }
            else {
                uint2 v = *(const uint2*)(prow + mt * 16 + l4 * 4);
                f32x4 a = {bf2f(v.x & 0xffffu), bf2f(v.x >> 16),
                           bf2f(v.y & 0xffffu), bf2f(v.y >> 16)};
                acc[mt] = a;
            }
        }
        // GEMM1: C1^T[c][pos] = W1t . X^T
        const float* frow = fusion + (size_t)ip * NDIN;
        f32x4 c1[4];
        #pragma unroll
        for (int mt = 0; mt < 4; ++mt) {
            f32x4 a = {b1r[mt][0], b1r[mt][1], b1r[mt][2], b1r[mt][3]};
            c1[mt] = a;
        }
        #pragma unroll
        for (int kt = 0; kt < 3; ++kt) {
            short8 xf = {0, 0, 0, 0, 0, 0, 0, 0};
            int d0 = kt * 32 + l4 * 8;
            if (d0 < 80) {
                fv4 a = __builtin_nontemporal_load((const fv4*)(frow + d0));
                fv4 bq = __builtin_nontemporal_load((const fv4*)(frow + d0 + 4));
                short8 s;
                s[0] = (short)f2bf(a.x);  s[1] = (short)f2bf(a.y);
                s[2] = (short)f2bf(a.z);  s[3] = (short)f2bf(a.w);
                s[4] = (short)f2bf(bq.x); s[5] = (short)f2bf(bq.y);
                s[6] = (short)f2bf(bq.z); s[7] = (short)f2bf(bq.w);
                xf = s;
            }
            #pragma unroll
            for (int mt = 0; mt < 4; ++mt) c1[mt] = MFMA16(w1f[mt][kt], xf, c1[mt]);
        }
        // relu -> bf16 -> swizzled LDS [pos][c] (rows stride 44 words)
        #pragma unroll
        for (int mt = 0; mt < 4; ++mt) {
            float x0 = fmaxf(c1[mt][0], 0.f), x1 = fmaxf(c1[mt][1], 0.f);
            float x2 = fmaxf(c1[mt][2], 0.f), x3 = fmaxf(c1[mt][3], 0.f);
            u32 lo = packbf2(x0, x1), hi = packbf2(x2, x3);
            int c0 = mt * 16 + l4 * 4;
            int gsw = (c0 >> 3) ^ (l15 & 7);
            *(u64*)(myl + l15 * 44 + gsw * 4 + ((c0 & 4) >> 1)) = (u64)lo | ((u64)hi << 32);
        }
        // GEMM2: S^T += Wbot . f1^T
        #pragma unroll
        for (int kt = 0; kt < 2; ++kt) {
            int gsw = (kt * 4 + l4) ^ (l15 & 7);
            short8 f1f = *(const short8*)(myl + l15 * 44 + gsw * 4);
            #pragma unroll
            for (int mt = 0; mt < 2; ++mt) acc[mt] = MFMA16(wbf[mt][kt], f1f, acc[mt]);
        }
        // stage outputs to LDS rows (overwrites f1 region; same-wave in-order DS)
        #pragma unroll
        for (int mt = 0; mt < 3; ++mt) {
            if (mt == 2 && l4 >= 2) continue;
            *(f32x4*)(myl + l15 * 44 + mt * 16 + l4 * 4) = acc[mt];
        }
        // cooperative coalesced write: 16 rows x 19 floats per head
        size_t o1 = (size_t)ipb * 19;
        #pragma unroll
        for (int s = 0; s < 5; ++s) {
            int f = lane + s * 64;
            if (f < 304) {
                u32 rr = (u32)f / 19u;
                u32 jj = (u32)f - rr * 19u;
                float v1 = __builtin_bit_cast(float, myl[rr * 44 + jj]);
                float v2 = __builtin_bit_cast(float, myl[rr * 44 + 20 + jj]);
                __builtin_nontemporal_store(v1, out + o1 + f);
                __builtin_nontemporal_store(v2, out + (size_t)NTOTP * 19 + o1 + f);
            }
        }
    }
}

// ================= fallback (tiny ws): direct path ==========================
__global__ void precompute_old(const float* __restrict__ W2, const float* __restrict__ b2,
                               const float* __restrict__ Wc1, const float* __restrict__ bc1,
                               float* __restrict__ wsA, float* __restrict__ wsc1) {
    int t = blockIdx.x * 256 + threadIdx.x;
    if (t < 128 * 20) {
        int k = t / 20, j = t % 20;
        float v = 0.f;
        if (j < 19) for (int c = 0; c < 64; ++c) v += W2[k * 64 + c] * Wc1[c * 19 + j];
        wsA[t] = v;
    } else if (t < 128 * 20 + 20) {
        int j = t - 128 * 20;
        float v = 0.f;
        if (j < 19) { v = bc1[j]; for (int c = 0; c < 64; ++c) v += b2[c] * Wc1[c * 19 + j]; }
        wsc1[j] = v;
    }
}

__device__ __forceinline__ void fma4o(float4& a, float s, const float4 b) {
    a.x = fmaf(s, b.x, a.x); a.y = fmaf(s, b.y, a.y);
    a.z = fmaf(s, b.z, a.z); a.w = fmaf(s, b.w, a.w);
}

__global__ __launch_bounds__(256) void fused_old(
    const float* __restrict__ feats, const float* __restrict__ fusion,
    const int* __restrict__ idx, const float* __restrict__ W1, const float* __restrict__ b1,
    const float* __restrict__ Wc2, const float* __restrict__ bc2,
    const float* __restrict__ wsA, const float* __restrict__ wsc1, float* __restrict__ out) {
    __shared__ __align__(16) float sW1[80 * 64];
    __shared__ __align__(16) float sA[128 * 20];
    __shared__ __align__(16) float sWc2[64 * 20];
    __shared__ __align__(16) float sb1[64];
    __shared__ __align__(16) float sc1[20];
    __shared__ __align__(16) float sbc2[20];
    int tid = threadIdx.x;
    for (int t = tid; t < 80 * 64; t += 256) sW1[t] = W1[t];
    for (int t = tid; t < 128 * 20; t += 256) sA[t] = wsA[t];
    for (int t = tid; t < 64 * 20; t += 256) {
        int k = t / 20, j = t % 20;
        sWc2[t] = (j < 19) ? Wc2[k * 19 + j] : 0.f;
    }
    if (tid < 64) sb1[tid] = b1[tid];
    if (tid < 20) sc1[tid] = wsc1[tid];
    if (tid < 20) sbc2[tid] = (tid < 19) ? bc2[tid] : 0.f;
    __syncthreads();
    int i0 = blockIdx.x * 256 + tid;
    bool act = (i0 < NTOTP);
    int i = act ? i0 : 0;
    int b = i / NPTS;
    int2 hw = ((const int2*)idx)[i];
    float4 f14[16];
    #pragma unroll
    for (int c4 = 0; c4 < 16; ++c4) f14[c4] = ((const float4*)sb1)[c4];
    const float4* fu4 = (const float4*)(fusion + (size_t)i * NDIN);
    for (int d4 = 0; d4 < NDIN / 4; ++d4) {
        float4 x = fu4[d4];
        const float* wr = sW1 + d4 * 256;
        #pragma unroll
        for (int c4 = 0; c4 < 16; ++c4) {
            fma4o(f14[c4], x.x, *(const float4*)(wr + c4 * 4));
            fma4o(f14[c4], x.y, *(const float4*)(wr + 64 + c4 * 4));
            fma4o(f14[c4], x.z, *(const float4*)(wr + 128 + c4 * 4));
            fma4o(f14[c4], x.w, *(const float4*)(wr + 192 + c4 * 4));
        }
    }
    #pragma unroll
    for (int c4 = 0; c4 < 16; ++c4) {
        f14[c4].x = fmaxf(f14[c4].x, 0.f); f14[c4].y = fmaxf(f14[c4].y, 0.f);
        f14[c4].z = fmaxf(f14[c4].z, 0.f); f14[c4].w = fmaxf(f14[c4].w, 0.f);
    }
    float4 s14[5], s24[5];
    #pragma unroll
    for (int j4 = 0; j4 < 5; ++j4) { s14[j4] = ((const float4*)sc1)[j4]; s24[j4] = ((const float4*)sbc2)[j4]; }
    const float* fb = feats + (size_t)b * CHW_ + (size_t)hw.x * NWID + hw.y;
    for (int k = 0; k < 64; ++k) {
        float g = fb[(size_t)k * HW_];
        const float4* ar = (const float4*)(sA + k * 20);
        const float4* cr = (const float4*)(sWc2 + k * 20);
        #pragma unroll
        for (int j4 = 0; j4 < 5; ++j4) { fma4o(s14[j4], g, ar[j4]); fma4o(s24[j4], g, cr[j4]); }
    }
    const float* f1s = (const float*)f14;
    for (int k = 0; k < 64; ++k) {
        float g = f1s[k];
        const float4* ar = (const float4*)(sA + (64 + k) * 20);
        #pragma unroll
        for (int j4 = 0; j4 < 5; ++j4) fma4o(s14[j4], g, ar[j4]);
    }
    if (act) {
        float* o1 = out + (size_t)i * 19;
        float* o2 = out + (size_t)NTOTP * 19 + (size_t)i * 19;
        const float* s1s = (const float*)s14;
        const float* s2s = (const float*)s24;
        #pragma unroll
        for (int j = 0; j < 19; ++j) o1[j] = s1s[j];
        #pragma unroll
        for (int j = 0; j < 19; ++j) o2[j] = s2s[j];
    }
}

// ================= launch ====================================================
extern "C" void kernel_launch(void* const* d_in, const int* in_sizes, int n_in,
                              void* d_out, int out_size, void* d_ws, size_t ws_size,
                              hipStream_t stream) {
    const float* feats  = (const float*)d_in[0];
    const float* fusion = (const float*)d_in[1];
    const int*   idx    = (const int*)d_in[2];
    const float* W1  = (const float*)d_in[3];
    const float* b1  = (const float*)d_in[4];
    const float* W2  = (const float*)d_in[5];
    const float* b2  = (const float*)d_in[6];
    const float* Wc1 = (const float*)d_in[7];
    const float* bc1 = (const float*)d_in[8];
    const float* Wc2 = (const float*)d_in[9];
    const float* bc2 = (const float*)d_in[10];
    float* out = (float*)d_out;
    char* ws = (char*)d_ws;

    if (ws_size >= WS_NEED) {
        u16*   Wproj = (u16*)(ws + OFF_WPROJ);
        u16*   W1t   = (u16*)(ws + OFF_W1T);
        u16*   Wbot  = (u16*)(ws + OFF_WBOT);
        float* cbias = (float*)(ws + OFF_CBIAS);
        u16*   proj  = (u16*)(ws + OFF_PROJ);
        prep_kernel<<<45, 256, 0, stream>>>(W1, W2, b2, Wc1, bc1, Wc2, bc2,
                                            Wproj, W1t, Wbot, cbias);
        proj_kernel<<<PROJ_NWG, 256, 0, stream>>>(feats, Wproj, cbias, proj);
        fused2_kernel<<<NTOTP / 128, 256, 0, stream>>>(fusion, idx, b1,
                                                       W1t, Wbot, proj, out);
    } else {
        float* wsA  = (float*)ws;
        float* wsc1 = wsA + 128 * 20;
        precompute_old<<<11, 256, 0, stream>>>(W2, b2, Wc1, bc1, wsA, wsc1);
        fused_old<<<(NTOTP + 255) / 256, 256, 0, stream>>>(feats, fusion, idx, W1, b1,
                                                           Wc2, bc2, wsA, wsc1, out);
    }
}